// Round 14
// baseline (305.766 us; speedup 1.0000x reference)
//
#include <hip/hip_runtime.h>
#include <hip/hip_bf16.h>

#define SLOW 32
#define MSG 16
#define TSTEPS 4
#define BATCH 8
#define NI0 256
#define NO0 128
#define NI1 128
#define NO1 64

typedef __bf16 bf16x8 __attribute__((ext_vector_type(8)));
typedef float f32x4 __attribute__((ext_vector_type(4)));

__device__ __forceinline__ float rcpf(float x) { return __builtin_amdgcn_rcpf(x); }
__device__ __forceinline__ float sigf(float x) { return rcpf(1.f + __expf(-x)); }
__device__ __forceinline__ float tanh_apx(float x) {
    float xc = fminf(fmaxf(x, -15.f), 15.f);
    float e = __expf(-2.f * xc);
    return (1.f - e) * rcpf(1.f + e);
}
__device__ __forceinline__ unsigned short f2bf(float x) {
    __bf16 h = (__bf16)x;
    return __builtin_bit_cast(unsigned short, h);
}
__device__ __forceinline__ float bf2f(unsigned short u) {
    __bf16 h = __builtin_bit_cast(__bf16, u);
    return (float)h;
}
__device__ __forceinline__ float sum16(float v) {
    v += __shfl_xor(v, 1); v += __shfl_xor(v, 2);
    v += __shfl_xor(v, 4); v += __shfl_xor(v, 8);
    return v;
}

// ---------------------------------------------------------------------------
// k_prep: pack B-fragments (bf16) for Wh (8 nt), Wf, Wb, Wi-fwd (8 nt, K pad)
// slot (lane l, elem e) = W[k=(l>>4)*8+e][nt*16+(l&15)]
// ---------------------------------------------------------------------------
__global__ void k_prep(const float* __restrict__ Wh, const float* __restrict__ Wf,
                       const float* __restrict__ Wb, const float* __restrict__ Wi,
                       unsigned short* __restrict__ WhBp,
                       unsigned short* __restrict__ WfBp,
                       unsigned short* __restrict__ WbBp,
                       unsigned short* __restrict__ WiFp) {
    int i = blockIdx.x * 256 + threadIdx.x;
    if (i < 4096) {
        int e = i & 7, l = (i >> 3) & 63, nt = i >> 9;
        int k = (l >> 4) * 8 + e, col = nt * 16 + (l & 15);
        WhBp[i] = f2bf(Wh[k * 128 + col]);
    } else if (i < 4608) {
        int j = i - 4096;
        int e = j & 7, l = j >> 3;
        int k = (l >> 4) * 8 + e;
        WfBp[j] = f2bf(Wf[k * 16 + (l & 15)]);
    } else if (i < 5120) {
        int j = i - 4608;
        int e = j & 7, l = j >> 3;
        int k = (l >> 4) * 8 + e;
        WbBp[j] = f2bf(Wb[k * 16 + (l & 15)]);
    } else if (i < 9216) {
        int j = i - 5120;
        int e = j & 7, l = (j >> 3) & 63, nt = j >> 9;
        int k = (l >> 4) * 8 + e, col = nt * 16 + (l & 15);
        WiFp[j] = (k < 16) ? f2bf(Wi[k * 128 + col]) : (unsigned short)0;
    }
}

// ---------------------------------------------------------------------------
// Layer 0: ONE-WAVE blocks. Grid = b*no*q*w4 = 8192. Wave owns 32 cells
// (2 m-tiles). No __syncthreads anywhere; weights live in VGPRs (per-lane
// B-fragments from global, L2-hot). nf -> 8 raw partials per (b,no).
// ---------------------------------------------------------------------------
__global__ __launch_bounds__(64) void k_l0(
    const float* __restrict__ inp, const float* __restrict__ Wi,
    const unsigned short* __restrict__ WhBp, const float* __restrict__ b_lstm,
    const unsigned short* __restrict__ WfBp, const float* __restrict__ bf_,
    const float* __restrict__ ln_fs, const float* __restrict__ ln_fb,
    unsigned short* __restrict__ h0bf, float* __restrict__ c0g,
    const float* __restrict__ nb1, float* __restrict__ nf_part, int t) {
    int bid = blockIdx.x;
    int w4 = bid & 3;
    int q = (bid >> 2) & 1;
    int no = (bid >> 3) & 127;
    int b = bid >> 10;
    int l = threadIdx.x, lo = l & 15, hg = l >> 4;

    __shared__ unsigned short Hbf[32 * 40];
    __shared__ float gsh[128];

    // per-lane weight fragments (registers)
    bf16x8 BWr[8];
#pragma unroll
    for (int nt = 0; nt < 8; nt++)
        BWr[nt] = *(const bf16x8*)&WhBp[(nt * 64 + l) * 8];

    // gate biases -> LDS (2 gates per lane); wave-local, no barrier needed
#pragma unroll
    for (int gi = 0; gi < 2; gi++) {
        int g = l + 64 * gi;
        float acc = b_lstm[g];
        if (t > 0) {
            const float* nbr = nb1 + ((size_t)b * NO0 + no) * MSG;
#pragma unroll
            for (int m = 0; m < MSG; m++) acc += nbr[m] * Wi[(MSG + m) * 128 + g];
        }
        gsh[g] = acc;
    }

    int cell0 = q * 128 + w4 * 32;
    float w8[8];
#pragma unroll
    for (int nt = 0; nt < 8; nt++) w8[nt] = Wi[lo + 16 * nt];
    f32x4 miv[2];
#pragma unroll
    for (int lt = 0; lt < 2; lt++)
#pragma unroll
        for (int r = 0; r < 4; r++)
            miv[lt][r] = inp[((size_t)t * BATCH + b) * NI0 + cell0 + lt * 16 + hg * 4 + r];

    // stage H (32 cells, 2 lanes per cell)
    {
        int lc = l >> 1, half = l & 1;
        unsigned int* hl = (unsigned int*)Hbf;
        if (t > 0) {
            const unsigned int* hsrc = (const unsigned int*)h0bf +
                ((size_t)(b * NO0 + no) * 256 + cell0 + lc) * 16 + half * 8;
#pragma unroll
            for (int j = 0; j < 8; j++) hl[lc * 20 + half * 8 + j] = hsrc[j];
        } else {
#pragma unroll
            for (int j = 0; j < 8; j++) hl[lc * 20 + half * 8 + j] = 0u;
        }
    }

    size_t cbase = (size_t)(b * NO0 + no) * 256 * 32;
    float cst[2][4][2];
    if (t > 0) {
#pragma unroll
        for (int lt = 0; lt < 2; lt++)
#pragma unroll
            for (int r = 0; r < 4; r++) {
                int gc = cell0 + lt * 16 + hg * 4 + r;
#pragma unroll
                for (int hi = 0; hi < 2; hi++)
                    cst[lt][r][hi] = c0g[cbase + (size_t)gc * 32 + lo + 16 * hi];
            }
    } else {
#pragma unroll
        for (int lt = 0; lt < 2; lt++)
#pragma unroll
            for (int r = 0; r < 4; r++) { cst[lt][r][0] = 0.f; cst[lt][r][1] = 0.f; }
    }

    float g8[8];
#pragma unroll
    for (int nt = 0; nt < 8; nt++) g8[nt] = gsh[lo + 16 * nt];

#pragma unroll
    for (int micro = 0; micro < 2; micro++) {
#pragma unroll
        for (int lt = 0; lt < 2; lt++) {
            bf16x8 A = *(const bf16x8*)&Hbf[(lt * 16 + lo) * 40 + hg * 8];
            f32x4 acc[4];
#pragma unroll
            for (int g = 0; g < 4; g++) {
                f32x4 ci = g8[2 * g] + miv[lt] * w8[2 * g];
                acc[g] = __builtin_amdgcn_mfma_f32_16x16x32_bf16(A, BWr[2 * g], ci, 0, 0, 0);
            }
#pragma unroll
            for (int r = 0; r < 4; r++) {
                int lrow = lt * 16 + hg * 4 + r;
                float cn = sigf(acc[1][r]) * cst[lt][r][0] + sigf(acc[0][r]) * tanh_apx(acc[2][r]);
                cst[lt][r][0] = cn;
                float hv = sigf(acc[3][r]) * tanh_apx(cn);
                Hbf[lrow * 40 + lo] = f2bf(hv);
                if (micro == 1)
                    c0g[cbase + (size_t)(cell0 + lrow) * 32 + lo] = cn;
            }
#pragma unroll
            for (int g = 0; g < 4; g++) {
                f32x4 ci = g8[2 * g + 1] + miv[lt] * w8[2 * g + 1];
                acc[g] = __builtin_amdgcn_mfma_f32_16x16x32_bf16(A, BWr[2 * g + 1], ci, 0, 0, 0);
            }
#pragma unroll
            for (int r = 0; r < 4; r++) {
                int lrow = lt * 16 + hg * 4 + r;
                float cn = sigf(acc[1][r]) * cst[lt][r][1] + sigf(acc[0][r]) * tanh_apx(acc[2][r]);
                cst[lt][r][1] = cn;
                float hv = sigf(acc[3][r]) * tanh_apx(cn);
                Hbf[lrow * 40 + lo + 16] = f2bf(hv);
                if (micro == 1)
                    c0g[cbase + (size_t)(cell0 + lrow) * 32 + lo + 16] = cn;
            }
        }
    }

    // epilogue: fm = LN(h @ Wf + bf); raw wave partial (k_l1 divides /256)
    bf16x8 Ff = *(const bf16x8*)&WfBp[l * 8];
    float lnfs = ln_fs[lo], lnfb = ln_fb[lo];
    float bfv = bf_[lo];
    f32x4 cif = {bfv, bfv, bfv, bfv};
    float nfp = 0.f;
#pragma unroll
    for (int lt = 0; lt < 2; lt++) {
        bf16x8 A = *(const bf16x8*)&Hbf[(lt * 16 + lo) * 40 + hg * 8];
        f32x4 f = __builtin_amdgcn_mfma_f32_16x16x32_bf16(A, Ff, cif, 0, 0, 0);
#pragma unroll
        for (int r = 0; r < 4; r++) {
            float x = f[r];
            float mean = sum16(x) * 0.0625f;
            float d = x - mean;
            float rs = rsqrtf(sum16(d * d) * 0.0625f + 1e-6f);
            nfp += d * rs * lnfs + lnfb;
        }
    }
    nfp += __shfl_xor(nfp, 16);
    nfp += __shfl_xor(nfp, 32);
    if (l < 16)
        nf_part[(((size_t)b * NO0 + no) * 8 + (q * 4 + w4)) * 16 + l] = nfp;

    // bulk coalesced h writeback
    {
        int lc = l >> 1, part = l & 1;
        unsigned int* hdst = (unsigned int*)h0bf +
            ((size_t)(b * NO0 + no) * 256 + cell0 + lc) * 16 + part * 8;
        const unsigned int* hl = (const unsigned int*)Hbf;
#pragma unroll
        for (int j = 0; j < 8; j++) hdst[j] = hl[lc * 20 + part * 8 + j];
    }
}

// ---------------------------------------------------------------------------
// Layer 1: ONE-WAVE blocks. Grid = b*no1*mt = 4096. Wave owns 16 cells.
// xf via MFMA (nf from 8 partials, WiF streamed from global). No barriers.
// ---------------------------------------------------------------------------
__global__ __launch_bounds__(64) void k_l1(
    const float* __restrict__ Wi, const unsigned short* __restrict__ WhBp,
    const float* __restrict__ b_lstm,
    const unsigned short* __restrict__ WfBp, const float* __restrict__ bf_,
    const float* __restrict__ ln_fs, const float* __restrict__ ln_fb,
    const unsigned short* __restrict__ WbBp, const float* __restrict__ bwb,
    const float* __restrict__ ln_bs, const float* __restrict__ ln_bb,
    const unsigned short* __restrict__ WiFp,
    unsigned short* __restrict__ h1bf, float* __restrict__ c1g,
    const float* __restrict__ nf_part, const float* __restrict__ gradP,
    const float* __restrict__ ohP,
    float* __restrict__ bm_g, float* __restrict__ outsum_part, int t) {
    int bid = blockIdx.x;
    int mt = bid & 7;
    int no = (bid >> 3) & 63;
    int b = bid >> 9;
    int l = threadIdx.x, lo = l & 15, hg = l >> 4;

    __shared__ unsigned short Hbf[16 * 40];
    __shared__ float gsh[128];

    bf16x8 BWr[8];
#pragma unroll
    for (int nt = 0; nt < 8; nt++)
        BWr[nt] = *(const bf16x8*)&WhBp[(nt * 64 + l) * 8];

#pragma unroll
    for (int gi = 0; gi < 2; gi++) {
        int g = l + 64 * gi;
        float acc = b_lstm[g];
        if (t > 0) {
            float gr = gradP[b * NO1 + no], oh = ohP[b * NO1 + no];
            acc += gr * Wi[MSG * 128 + g] + oh * Wi[(MSG + 1) * 128 + g];
        }
        gsh[g] = acc;
    }

    // stage H (16 cells, 4 lanes per cell)
    {
        int lc = l >> 2, part = l & 3;
        unsigned int* hl = (unsigned int*)Hbf;
        if (t > 0) {
            const unsigned int* hsrc = (const unsigned int*)h1bf +
                ((size_t)(b * NO1 + no) * 128 + mt * 16 + lc) * 16 + part * 4;
#pragma unroll
            for (int j = 0; j < 4; j++) hl[lc * 20 + part * 4 + j] = hsrc[j];
        } else {
#pragma unroll
            for (int j = 0; j < 4; j++) hl[lc * 20 + part * 4 + j] = 0u;
        }
    }

    size_t cbase = (size_t)(b * NO1 + no) * 128 * 32;
    float cst[4][2];
    if (t > 0) {
#pragma unroll
        for (int r = 0; r < 4; r++) {
            int gc = mt * 16 + hg * 4 + r;
#pragma unroll
            for (int hi = 0; hi < 2; hi++)
                cst[r][hi] = c1g[cbase + (size_t)gc * 32 + lo + 16 * hi];
        }
    } else {
#pragma unroll
        for (int r = 0; r < 4; r++) { cst[r][0] = 0.f; cst[r][1] = 0.f; }
    }

    // nf A-fragment: row = cell (mt*16+lo), k-slot = m (hg<2 lanes), else 0
    bf16x8 Anf;
#pragma unroll
    for (int e = 0; e < 8; e++) Anf[e] = (__bf16)0.f;
    if (hg < 2) {
        const float* p = nf_part + ((size_t)b * NO0 + mt * 16 + lo) * 128;
        float s[8];
#pragma unroll
        for (int e = 0; e < 8; e++) s[e] = 0.f;
#pragma unroll
        for (int j = 0; j < 8; j++) {
            float4 a0 = *(const float4*)&p[j * 16 + hg * 8];
            float4 a1 = *(const float4*)&p[j * 16 + hg * 8 + 4];
            s[0] += a0.x; s[1] += a0.y; s[2] += a0.z; s[3] += a0.w;
            s[4] += a1.x; s[5] += a1.y; s[6] += a1.z; s[7] += a1.w;
        }
#pragma unroll
        for (int e = 0; e < 8; e++) Anf[e] = (__bf16)(s[e] * (1.f / 256.f));
    }

    // xf via MFMA (WiF fragments streamed from global; one-shot)
    f32x4 xf4[8];
    {
        f32x4 zz = {0.f, 0.f, 0.f, 0.f};
#pragma unroll
        for (int nt = 0; nt < 8; nt++) {
            bf16x8 B = *(const bf16x8*)&WiFp[(nt * 64 + l) * 8];
            xf4[nt] = __builtin_amdgcn_mfma_f32_16x16x32_bf16(Anf, B, zz, 0, 0, 0);
        }
    }
    float g8[8];
#pragma unroll
    for (int nt = 0; nt < 8; nt++) g8[nt] = gsh[lo + 16 * nt];

#pragma unroll
    for (int micro = 0; micro < 2; micro++) {
        bf16x8 A = *(const bf16x8*)&Hbf[lo * 40 + hg * 8];
        f32x4 acc[4];
#pragma unroll
        for (int g = 0; g < 4; g++) {
            f32x4 ci = xf4[2 * g] + g8[2 * g];
            acc[g] = __builtin_amdgcn_mfma_f32_16x16x32_bf16(A, BWr[2 * g], ci, 0, 0, 0);
        }
#pragma unroll
        for (int r = 0; r < 4; r++) {
            int gc = mt * 16 + hg * 4 + r;
            float cn = sigf(acc[1][r]) * cst[r][0] + sigf(acc[0][r]) * tanh_apx(acc[2][r]);
            cst[r][0] = cn;
            float hv = sigf(acc[3][r]) * tanh_apx(cn);
            Hbf[(hg * 4 + r) * 40 + lo] = f2bf(hv);
            if (micro == 1)
                c1g[cbase + (size_t)gc * 32 + lo] = cn;
        }
#pragma unroll
        for (int g = 0; g < 4; g++) {
            f32x4 ci = xf4[2 * g + 1] + g8[2 * g + 1];
            acc[g] = __builtin_amdgcn_mfma_f32_16x16x32_bf16(A, BWr[2 * g + 1], ci, 0, 0, 0);
        }
#pragma unroll
        for (int r = 0; r < 4; r++) {
            int gc = mt * 16 + hg * 4 + r;
            float cn = sigf(acc[1][r]) * cst[r][1] + sigf(acc[0][r]) * tanh_apx(acc[2][r]);
            cst[r][1] = cn;
            float hv = sigf(acc[3][r]) * tanh_apx(cn);
            Hbf[(hg * 4 + r) * 40 + lo + 16] = f2bf(hv);
            if (micro == 1)
                c1g[cbase + (size_t)gc * 32 + lo + 16] = cn;
        }
    }

    // epilogue: fm (channel 0 -> partial) and bm (-> bm_g)
    bf16x8 Ff = *(const bf16x8*)&WfBp[l * 8];
    bf16x8 Bb = *(const bf16x8*)&WbBp[l * 8];
    float lnfs = ln_fs[lo], lnfb = ln_fb[lo];
    float lnbs = ln_bs[lo], lnbb = ln_bb[lo];
    float bfv = bf_[lo], bwv = bwb[lo];
    f32x4 cif = {bfv, bfv, bfv, bfv};
    f32x4 cib = {bwv, bwv, bwv, bwv};
    float op = 0.f;
    {
        bf16x8 A = *(const bf16x8*)&Hbf[lo * 40 + hg * 8];
        f32x4 f = __builtin_amdgcn_mfma_f32_16x16x32_bf16(A, Ff, cif, 0, 0, 0);
        f32x4 g = __builtin_amdgcn_mfma_f32_16x16x32_bf16(A, Bb, cib, 0, 0, 0);
#pragma unroll
        for (int r = 0; r < 4; r++) {
            int gc = mt * 16 + hg * 4 + r;
            {
                float x = f[r];
                float mean = sum16(x) * 0.0625f;
                float d = x - mean;
                float rs = rsqrtf(sum16(d * d) * 0.0625f + 1e-6f);
                op += d * rs * lnfs + lnfb;
            }
            {
                float x = g[r];
                float mean = sum16(x) * 0.0625f;
                float d = x - mean;
                float rs = rsqrtf(sum16(d * d) * 0.0625f + 1e-6f);
                bm_g[(((size_t)b * NO1 + no) * MSG + lo) * NI1 + gc] = d * rs * lnbs + lnbb;
            }
        }
    }
    op += __shfl_xor(op, 16);
    op += __shfl_xor(op, 32);
    if (l == 0)
        outsum_part[((size_t)b * NO1 + no) * 8 + mt] = op;

    // bulk coalesced h writeback
    {
        int lc = l >> 2, part = l & 3;
        unsigned int* hdst = (unsigned int*)h1bf +
            ((size_t)(b * NO1 + no) * 128 + mt * 16 + lc) * 16 + part * 4;
        const unsigned int* hl = (const unsigned int*)Hbf;
#pragma unroll
        for (int j = 0; j < 4; j++) hdst[j] = hl[lc * 20 + part * 4 + j];
    }
}

// ---------------------------------------------------------------------------
// k_step_end: fused between-step work:
//   blocks [0,1920)    : batch-merge of h/c slow channels s<16
//   blocks [1920,1984) : nb1[b][ni][m] = mean over no1 of bm_g
//   blocks [1984,1992) : softmax/error
// ---------------------------------------------------------------------------
__global__ __launch_bounds__(256) void k_step_end(
    unsigned int* __restrict__ h0, float* __restrict__ c0,
    unsigned int* __restrict__ h1, float* __restrict__ c1,
    const float* __restrict__ bm_g, float* __restrict__ nb1,
    const float* __restrict__ outsum_part, const int* __restrict__ labels,
    float* __restrict__ dout, float* __restrict__ gradP,
    float* __restrict__ ohP, int t) {
    int bid = blockIdx.x;
    if (bid < 1920) {
        int idx = bid * 256 + threadIdx.x;
        if (idx < 262144) {  // l0 h
            int u = idx & 7, cell = (idx >> 3) & 255, no = idx >> 11;
            size_t base = ((size_t)no * 256 + cell) * 16 + u;
            const size_t strd = (size_t)128 * 256 * 16;
            float s0 = 0.f, s1 = 0.f;
#pragma unroll
            for (int b = 0; b < 8; b++) {
                unsigned int v = h0[base + b * strd];
                s0 += bf2f((unsigned short)(v & 0xffff));
                s1 += bf2f((unsigned short)(v >> 16));
            }
            unsigned int mv = (unsigned int)f2bf(s0 * 0.125f) |
                              ((unsigned int)f2bf(s1 * 0.125f) << 16);
#pragma unroll
            for (int b = 0; b < 8; b++) h0[base + b * strd] = mv;
            return;
        }
        idx -= 262144;
        if (idx < 131072) {  // l0 c
            int s4 = idx & 3, cell = (idx >> 2) & 255, no = idx >> 10;
            float4* C = (float4*)c0;
            size_t base = ((size_t)no * 256 + cell) * 8 + s4;
            const size_t strd = (size_t)128 * 256 * 8;
            float4 a = {0.f, 0.f, 0.f, 0.f};
#pragma unroll
            for (int b = 0; b < 8; b++) {
                float4 v = C[base + b * strd];
                a.x += v.x; a.y += v.y; a.z += v.z; a.w += v.w;
            }
            a.x *= 0.125f; a.y *= 0.125f; a.z *= 0.125f; a.w *= 0.125f;
#pragma unroll
            for (int b = 0; b < 8; b++) C[base + b * strd] = a;
            return;
        }
        idx -= 131072;
        if (idx < 65536) {  // l1 h
            int u = idx & 7, cell = (idx >> 3) & 127, no = idx >> 10;
            size_t base = ((size_t)no * 128 + cell) * 16 + u;
            const size_t strd = (size_t)64 * 128 * 16;
            float s0 = 0.f, s1 = 0.f;
#pragma unroll
            for (int b = 0; b < 8; b++) {
                unsigned int v = h1[base + b * strd];
                s0 += bf2f((unsigned short)(v & 0xffff));
                s1 += bf2f((unsigned short)(v >> 16));
            }
            unsigned int mv = (unsigned int)f2bf(s0 * 0.125f) |
                              ((unsigned int)f2bf(s1 * 0.125f) << 16);
#pragma unroll
            for (int b = 0; b < 8; b++) h1[base + b * strd] = mv;
            return;
        }
        idx -= 65536;
        {  // l1 c
            int s4 = idx & 3, cell = (idx >> 2) & 127, no = idx >> 9;
            float4* C = (float4*)c1;
            size_t base = ((size_t)no * 128 + cell) * 8 + s4;
            const size_t strd = (size_t)64 * 128 * 8;
            float4 a = {0.f, 0.f, 0.f, 0.f};
#pragma unroll
            for (int b = 0; b < 8; b++) {
                float4 v = C[base + b * strd];
                a.x += v.x; a.y += v.y; a.z += v.z; a.w += v.w;
            }
            a.x *= 0.125f; a.y *= 0.125f; a.z *= 0.125f; a.w *= 0.125f;
#pragma unroll
            for (int b = 0; b < 8; b++) C[base + b * strd] = a;
        }
        return;
    }
    if (bid < 1984) {
        int g = (bid - 1920) * 256 + threadIdx.x;  // < 16384
        int ni = g & 127;
        int m = (g >> 7) & 15;
        int b = g >> 11;
        float a = 0.f;
#pragma unroll 8
        for (int no = 0; no < NO1; no++)
            a += bm_g[(((size_t)b * NO1 + no) * MSG + m) * NI1 + ni];
        nb1[((size_t)b * NI1 + ni) * MSG + m] = a * (1.f / NO1);
        return;
    }
    {
        int b = bid - 1984;
        int no = threadIdx.x;
        if (no < 64) {
            const float* p = outsum_part + ((size_t)b * NO1 + no) * 8;
            float v = 0.f;
#pragma unroll
            for (int j = 0; j < 8; j++) v += p[j];
            v *= (1.f / 128.f);
            float mx = v;
#pragma unroll
            for (int d = 1; d < 64; d <<= 1) mx = fmaxf(mx, __shfl_xor(mx, d));
            float e = __expf(v - mx);
            float sum = e;
#pragma unroll
            for (int d = 1; d < 64; d <<= 1) sum += __shfl_xor(sum, d);
            int lbl = labels[t * BATCH + b];
            float oh = (no == lbl) ? 1.f : 0.f;
            gradP[b * NO1 + no] = e / sum - oh;
            ohP[b * NO1 + no] = oh;
            dout[((size_t)t * BATCH + b) * NO1 + no] = v;
        }
    }
}

// ---------------------------------------------------------------------------

extern "C" void kernel_launch(void* const* d_in, const int* in_sizes, int n_in,
                              void* d_out, int out_size, void* d_ws, size_t ws_size,
                              hipStream_t stream) {
    const float* inp   = (const float*)d_in[0];
    const int*   labels= (const int*)d_in[1];
    const float* Wi    = (const float*)d_in[2];
    const float* Wh    = (const float*)d_in[3];
    const float* b_lstm= (const float*)d_in[4];
    const float* Wf    = (const float*)d_in[5];
    const float* bf_   = (const float*)d_in[6];
    const float* Wb    = (const float*)d_in[7];
    const float* bwb   = (const float*)d_in[8];
    const float* ln_fs = (const float*)d_in[9];
    const float* ln_fb = (const float*)d_in[10];
    const float* ln_bs = (const float*)d_in[11];
    const float* ln_bb = (const float*)d_in[12];
    float* out = (float*)d_out;

    const size_t SZ0 = (size_t)BATCH * NO0 * 256 * 32;  // 8,388,608
    const size_t SZ1 = (size_t)BATCH * NO1 * 128 * 32;  // 2,097,152

    float* c0 = (float*)d_ws;
    float* c1 = c0 + SZ0;
    unsigned short* h0bf = (unsigned short*)(c1 + SZ1);
    unsigned short* h1bf = h0bf + SZ0;
    float* bm_g        = (float*)(h1bf + SZ1);          // 1,048,576 f
    float* nf_part     = bm_g + 1048576;                // 131,072 f
    float* nb1         = nf_part + 131072;              // 16,384 f
    float* outsum_part = nb1 + 16384;                   // 4,096 f
    float* gradP       = outsum_part + 4096;            // 512
    float* ohP         = gradP + 512;                   // 512
    unsigned short* WhBp = (unsigned short*)(ohP + 512);
    unsigned short* WfBp = WhBp + 4096;
    unsigned short* WbBp = WfBp + 512;
    unsigned short* WiFp = WbBp + 512;                  // 4096

    k_prep<<<36, 256, 0, stream>>>(Wh, Wf, Wb, Wi, WhBp, WfBp, WbBp, WiFp);

    for (int t = 0; t < TSTEPS; t++) {
        k_l0<<<BATCH * NO0 * 2 * 4, 64, 0, stream>>>(inp, Wi, WhBp, b_lstm, WfBp, bf_,
                                                     ln_fs, ln_fb, h0bf, c0, nb1,
                                                     nf_part, t);
        k_l1<<<BATCH * NO1 * 8, 64, 0, stream>>>(Wi, WhBp, b_lstm, WfBp, bf_,
                                                 ln_fs, ln_fb, WbBp, bwb, ln_bs, ln_bb,
                                                 WiFp, h1bf, c1, nf_part, gradP, ohP,
                                                 bm_g, outsum_part, t);
        k_step_end<<<1992, 256, 0, stream>>>((unsigned int*)h0bf, c0,
                                             (unsigned int*)h1bf, c1,
                                             bm_g, nb1, outsum_part, labels,
                                             out, gradP, ohP, t);
    }
}